// Round 3
// baseline (442.291 us; speedup 1.0000x reference)
//
#include <hip/hip_runtime.h>
#include <hip/hip_bf16.h>
#include <math.h>

#define N_NODES 100000
#define DIM 64
#define E_EDGES 1600000
#define N_ADJ 4
#define NB 1563              // ceil(100000/64) buckets of 64 rows
#define NBTOT (N_ADJ * NB)   // 6252
#define P1_BLK 1024
#define P1_CHUNK 12800
#define P1_GRIDX 125         // 125 * 12800 = 1.6M
#define SORT_STAGE 4096      // per-bucket LDS stage; mean load 1024
#define NVOFF ((u32)N_NODES * DIM)   // u16 elements between s0 and s1

typedef unsigned short u16;
typedef unsigned int u32;

// ---- used-adjacency mask from device-side idxes ----
__global__ void mask_kernel(const int* __restrict__ iseq,
                            const int* __restrict__ ires,
                            int* __restrict__ used) {
    if (threadIdx.x == 0) {
        used[0] = used[1] = used[2] = used[3] = 0;
        used[iseq[0]] = 1; used[iseq[1]] = 1;
        used[iseq[2]] = 1; used[iseq[3]] = 1;
        used[ires[0]] = 1; used[ires[1]] = 1;
    }
}

// ---------------- GEMM: s0 = bf16(x @ W + b) ----------------
__global__ __launch_bounds__(256) void gemm_kernel(
    const float* __restrict__ x, const float* __restrict__ W,
    const float* __restrict__ b, u16* __restrict__ h) {
    __shared__ float Ws[DIM * DIM];
    __shared__ float xs[16 * DIM];
    const int tid = threadIdx.x;
    const long row0 = (long)blockIdx.x * 16;
    for (int i = tid; i < DIM * DIM; i += 256) Ws[i] = W[i];
    for (int i = tid; i < 16 * DIM; i += 256) xs[i] = x[row0 * DIM + i];
    __syncthreads();
    const int lane = tid & 63;
    const int grp  = tid >> 6;
    const float bias = b[lane];
    #pragma unroll
    for (int rr = 0; rr < 4; ++rr) {
        const int r = grp * 4 + rr;
        float acc = bias;
        #pragma unroll
        for (int k = 0; k < DIM; ++k)
            acc += xs[r * DIM + k] * Ws[k * DIM + lane];
        __hip_bfloat16 hb = __float2bfloat16(acc);
        h[(row0 + r) * DIM + lane] = *(u16*)&hb;
    }
}

// ---- hist: LDS-aggregated bucket counts -> gcnt ----
__global__ __launch_bounds__(1024) void hist_kernel(
    const int* __restrict__ rows, int* __restrict__ gcnt,
    const int* __restrict__ used) {
    __shared__ int h[NB];
    const int a = blockIdx.y;
    if (!used[a]) return;
    const int tid = threadIdx.x;
    const long e0 = (long)a * E_EDGES + (long)blockIdx.x * P1_CHUNK;
    for (int i = tid; i < NB; i += P1_BLK) h[i] = 0;
    __syncthreads();
    for (int i = tid; i < P1_CHUNK; i += P1_BLK)
        atomicAdd(&h[rows[e0 + i] >> 6], 1);
    __syncthreads();
    for (int bk = tid; bk < NB; bk += P1_BLK) {
        const int c = h[bk];
        if (c) atomicAdd(&gcnt[a * NB + bk], c);
    }
}

// ---- scan: exact exclusive scan of 6252 bucket counts (1 block) ----
__global__ __launch_bounds__(1024) void scan_kernel(
    const int* __restrict__ gcnt, int* __restrict__ bbase,
    int* __restrict__ cursor) {
    __shared__ int wsum[16];
    const int tid = threadIdx.x, lane = tid & 63, wave = tid >> 6;
    int pre[7];
    int tsum = 0;
    #pragma unroll
    for (int k = 0; k < 7; ++k) {
        const int idx = tid * 7 + k;
        const int v = (idx < NBTOT) ? gcnt[idx] : 0;
        pre[k] = tsum;
        tsum += v;
    }
    int incl = tsum;
    #pragma unroll
    for (int o = 1; o < 64; o <<= 1) {
        const int t = __shfl_up(incl, o);
        if (lane >= o) incl += t;
    }
    if (lane == 63) wsum[wave] = incl;
    __syncthreads();
    if (tid == 0) {
        int run = 0;
        #pragma unroll
        for (int w = 0; w < 16; ++w) { const int t = wsum[w]; wsum[w] = run; run += t; }
    }
    __syncthreads();
    const int texcl = incl - tsum + wsum[wave];
    #pragma unroll
    for (int k = 0; k < 7; ++k) {
        const int idx = tid * 7 + k;
        if (idx < NBTOT) {
            const int v = texcl + pre[k];
            bbase[idx]  = v;
            cursor[idx] = v;
        }
    }
    if (tid == 0) bbase[NBTOT] = N_ADJ * E_EDGES;
}

// ---- place: reserve per-(block,bucket) runs, pack edges ----
__global__ __launch_bounds__(1024) void place_kernel(
    const int* __restrict__ rows, const int* __restrict__ cols,
    const float* __restrict__ vals, int* __restrict__ cursor,
    int2* __restrict__ bins, const int* __restrict__ used) {
    __shared__ int h[NB];
    const int a = blockIdx.y;
    if (!used[a]) return;
    const int tid = threadIdx.x;
    const long e0 = (long)a * E_EDGES + (long)blockIdx.x * P1_CHUNK;
    for (int i = tid; i < NB; i += P1_BLK) h[i] = 0;
    __syncthreads();
    for (int i = tid; i < P1_CHUNK; i += P1_BLK)
        atomicAdd(&h[rows[e0 + i] >> 6], 1);
    __syncthreads();
    for (int bk = tid; bk < NB; bk += P1_BLK) {
        const int c = h[bk];
        if (c) h[bk] = atomicAdd(&cursor[a * NB + bk], c);  // abs base of run
    }
    __syncthreads();
    for (int i = tid; i < P1_CHUNK; i += P1_BLK) {
        const int r  = rows[e0 + i];
        const int bk = r >> 6;
        const int slot = atomicAdd(&h[bk], 1);              // absolute bins index
        bins[slot] = make_int2((cols[e0 + i] << 6) | (r & 63),
                               __float_as_int(vals[e0 + i]));
    }
}

// ---- sort: per-bucket counting sort by row&63, emit per-row (start,count) ----
__global__ __launch_bounds__(256) void sort_kernel(
    int2* __restrict__ bins, const int* __restrict__ bbase,
    int2* __restrict__ rowinfo, const int* __restrict__ used) {
    __shared__ int2 stage[SORT_STAGE];
    __shared__ int h[64], off[64], cur[64];
    const int a   = blockIdx.x / NB;
    if (!used[a]) return;
    const int tid = threadIdx.x;
    const int bk  = blockIdx.x % NB;
    const int p0  = bbase[blockIdx.x];
    const int n   = min(bbase[blockIdx.x + 1] - p0, SORT_STAGE);

    if (tid < 64) h[tid] = 0;
    __syncthreads();
    for (int i = tid; i < n; i += 256) {
        const int2 e = bins[p0 + i];
        stage[i] = e;
        atomicAdd(&h[e.x & 63], 1);
    }
    __syncthreads();
    if (tid < 64) {
        const int v = h[tid];
        int incl = v;
        #pragma unroll
        for (int o = 1; o < 64; o <<= 1) {
            const int t = __shfl_up(incl, o);
            if (tid >= o) incl += t;
        }
        off[tid] = incl - v;
        cur[tid] = incl - v;
    }
    __syncthreads();
    for (int i = tid; i < n; i += 256) {
        const int2 e = stage[i];
        const int rank = atomicAdd(&cur[e.x & 63], 1);
        bins[p0 + rank] = e;
    }
    if (tid < 64) {
        const int row = bk * 64 + tid;
        if (row < N_NODES)
            rowinfo[a * N_NODES + row] = make_int2(p0 + off[tid], h[tid]);
    }
}

// ---------------- Unified pull gather core (record-per-lane) ----------------
// Wave = 1 row. Per 64-edge super-iteration: EACH LANE loads one distinct
// edge record (cascade + bins load run once per 64 edges, not once per
// 8-lane group). Slots s=0..7 then distribute edge (s*8+grp)'s packed
// column-offset and value via ds_bpermute (immediate byte offset s*32);
// the 8 lanes of each group gather 8 dims each (uint4) and FMA.
// Source lane folds (col<<6 & mask) + segment src offset; receiver adds
// its own dim offset dsub. Lanes with t >= m publish (0, 0.0f): harmless
// row-0 gather times zero.
__device__ __forceinline__ void gather4(
    const u16* __restrict__ base, const u32 nvoff,
    const int2* __restrict__ bins,
    const int2 i0, const int2 i1, const int2 i2, const int2 i3,
    const int lane, const int grp, const int dsub, float acc[8])
{
    const int c1 = i0.y;
    const int c2 = c1 + i1.y;
    const int c3 = c2 + i2.y;
    const int m  = c3 + i3.y;
    const int b0 = i0.x;
    const int b1 = i1.x - c1;
    const int b2 = i2.x - c2;
    const int b3 = i3.x - c3;
    const int bp = grp << 2;          // bpermute byte base for this group

    for (int t0 = 0; t0 < m; t0 += 64) {
        const int t = t0 + lane;
        u32  xm = 0u;
        float v = 0.f;
        if (t < m) {
            int pos = b0 + t;
            if (t >= c1) pos = b1 + t;
            if (t >= c2) pos = b2 + t;
            if (t >= c3) pos = b3 + t;
            const long long raw =
                __builtin_nontemporal_load((const long long*)(bins + pos));
            const int x = (int)raw;
            v  = __int_as_float((int)(raw >> 32));
            xm = ((u32)x & 0xFFFFFFC0u) + ((t < c2) ? nvoff : 0u);
        }
        const int mrem = m - t0;
        #pragma unroll
        for (int s = 0; s < 8; ++s) {
            if ((s << 3) >= mrem) break;
            const u32 xs = (u32)__builtin_amdgcn_ds_bpermute(bp + (s << 5), (int)xm);
            const float vs = __int_as_float(
                __builtin_amdgcn_ds_bpermute(bp + (s << 5), __float_as_int(v)));
            const uint4 w = *(const uint4*)(base + (xs + (u32)dsub));
            acc[0] = fmaf(vs, __int_as_float(w.x << 16),         acc[0]);
            acc[1] = fmaf(vs, __int_as_float(w.x & 0xffff0000u), acc[1]);
            acc[2] = fmaf(vs, __int_as_float(w.y << 16),         acc[2]);
            acc[3] = fmaf(vs, __int_as_float(w.y & 0xffff0000u), acc[3]);
            acc[4] = fmaf(vs, __int_as_float(w.z << 16),         acc[4]);
            acc[5] = fmaf(vs, __int_as_float(w.z & 0xffff0000u), acc[5]);
            acc[6] = fmaf(vs, __int_as_float(w.w << 16),         acc[6]);
            acc[7] = fmaf(vs, __int_as_float(w.w & 0xffff0000u), acc[7]);
        }
    }
}

__device__ __forceinline__ void reduce_groups8(float acc[8]) {
    #pragma unroll
    for (int d = 0; d < 8; ++d) {
        acc[d] += __shfl_xor(acc[d], 8);
        acc[d] += __shfl_xor(acc[d], 16);
        acc[d] += __shfl_xor(acc[d], 32);
    }
}

// s1 = bf16(0.5*(A[i0]+A[i1]) @ s0)
__global__ __launch_bounds__(256) void gather_op_kernel(
    const u16* __restrict__ s0, u16* __restrict__ dst,
    const int2* __restrict__ bins, const int2* __restrict__ rowinfo,
    const int* __restrict__ idx) {
    const int lane = threadIdx.x & 63;
    const int row  = blockIdx.x * 4 + (threadIdx.x >> 6);
    const int grp  = lane >> 3;
    const int sub  = lane & 7;
    const int dsub = sub << 3;
    const int2 i0 = rowinfo[idx[0] * N_NODES + row];
    const int2 i1 = rowinfo[idx[1] * N_NODES + row];
    const int2 iz = make_int2(0, 0);
    float acc[8] = {0.f, 0.f, 0.f, 0.f, 0.f, 0.f, 0.f, 0.f};
    gather4(s0, 0u, bins, i0, i1, iz, iz, lane, grp, dsub, acc);
    reduce_groups8(acc);
    if (grp == 0) {
        u32 p[4];
        #pragma unroll
        for (int q = 0; q < 4; ++q) {
            __hip_bfloat16 blo = __float2bfloat16(0.5f * acc[2 * q]);
            __hip_bfloat16 bhi = __float2bfloat16(0.5f * acc[2 * q + 1]);
            p[q] = (u32)(*(u16*)&blo) | ((u32)(*(u16*)&bhi) << 16);
        }
        *(uint4*)(dst + (long)row * DIM + dsub) = make_uint4(p[0], p[1], p[2], p[3]);
    }
}

// out = gelu(LN(0.5*(seq@s1) + 0.5*(res@s0)))
__global__ __launch_bounds__(256) void fused_op_ln_gelu_kernel(
    const u16* __restrict__ s0, float* __restrict__ out,
    const int2* __restrict__ bins, const int2* __restrict__ rowinfo,
    const int* __restrict__ idx_seq1, const int* __restrict__ idx_res,
    const float* __restrict__ gamma, const float* __restrict__ beta) {
    const int lane = threadIdx.x & 63;
    const int row  = blockIdx.x * 4 + (threadIdx.x >> 6);
    const int grp  = lane >> 3;
    const int sub  = lane & 7;
    const int dsub = sub << 3;
    // segments 0,1 gather from s1 (= s0 + NVOFF, selected via nvoff), 2,3 from s0
    const int2 i0 = rowinfo[idx_seq1[0] * N_NODES + row];
    const int2 i1 = rowinfo[idx_seq1[1] * N_NODES + row];
    const int2 i2 = rowinfo[idx_res[0]  * N_NODES + row];
    const int2 i3 = rowinfo[idx_res[1]  * N_NODES + row];
    float acc[8] = {0.f, 0.f, 0.f, 0.f, 0.f, 0.f, 0.f, 0.f};
    gather4(s0, NVOFF, bins, i0, i1, i2, i3, lane, grp, dsub, acc);
    reduce_groups8(acc);
    #pragma unroll
    for (int d = 0; d < 8; ++d) acc[d] *= 0.5f;
    float s = 0.f, s2 = 0.f;
    #pragma unroll
    for (int d = 0; d < 8; ++d) { s += acc[d]; s2 += acc[d] * acc[d]; }
    s  += __shfl_xor(s, 1);  s  += __shfl_xor(s, 2);  s  += __shfl_xor(s, 4);
    s2 += __shfl_xor(s2, 1); s2 += __shfl_xor(s2, 2); s2 += __shfl_xor(s2, 4);
    const float mu  = s * (1.0f / DIM);
    const float var = s2 * (1.0f / DIM) - mu * mu;
    const float inv = rsqrtf(var + 1e-5f);
    if (grp == 0) {
        const float4 gm0 = ((const float4*)gamma)[sub * 2];
        const float4 gm1 = ((const float4*)gamma)[sub * 2 + 1];
        const float4 bt0 = ((const float4*)beta)[sub * 2];
        const float4 bt1 = ((const float4*)beta)[sub * 2 + 1];
        float y[8];
        y[0] = (acc[0] - mu) * inv * gm0.x + bt0.x;
        y[1] = (acc[1] - mu) * inv * gm0.y + bt0.y;
        y[2] = (acc[2] - mu) * inv * gm0.z + bt0.z;
        y[3] = (acc[3] - mu) * inv * gm0.w + bt0.w;
        y[4] = (acc[4] - mu) * inv * gm1.x + bt1.x;
        y[5] = (acc[5] - mu) * inv * gm1.y + bt1.y;
        y[6] = (acc[6] - mu) * inv * gm1.z + bt1.z;
        y[7] = (acc[7] - mu) * inv * gm1.w + bt1.w;
        float4 o0, o1;
        o0.x = 0.5f * y[0] * (1.0f + erff(y[0] * 0.70710678118654752f));
        o0.y = 0.5f * y[1] * (1.0f + erff(y[1] * 0.70710678118654752f));
        o0.z = 0.5f * y[2] * (1.0f + erff(y[2] * 0.70710678118654752f));
        o0.w = 0.5f * y[3] * (1.0f + erff(y[3] * 0.70710678118654752f));
        o1.x = 0.5f * y[4] * (1.0f + erff(y[4] * 0.70710678118654752f));
        o1.y = 0.5f * y[5] * (1.0f + erff(y[5] * 0.70710678118654752f));
        o1.z = 0.5f * y[6] * (1.0f + erff(y[6] * 0.70710678118654752f));
        o1.w = 0.5f * y[7] * (1.0f + erff(y[7] * 0.70710678118654752f));
        float4* po = (float4*)(out + (long)row * DIM + dsub);
        po[0] = o0;
        po[1] = o1;
    }
}

extern "C" void kernel_launch(void* const* d_in, const int* in_sizes, int n_in,
                              void* d_out, int out_size, void* d_ws, size_t ws_size,
                              hipStream_t stream) {
    const float* x     = (const float*)d_in[0];
    const float* W     = (const float*)d_in[1];
    const float* b     = (const float*)d_in[2];
    const int*   rows  = (const int*)d_in[3];
    const int*   cols  = (const int*)d_in[4];
    const float* vals  = (const float*)d_in[5];
    const float* gamma = (const float*)d_in[6];
    const float* beta  = (const float*)d_in[7];
    const int*   idxes_seq = (const int*)d_in[8];   // [2,2] flat
    const int*   idxes_res = (const int*)d_in[9];   // [1,2] flat
    float* out = (float*)d_out;

    // workspace layout: ~80 MB total
    int2*  bins    = (int2*)d_ws;                                // 4E int2 = 51.2 MB
    u16*   s0      = (u16*)(bins + (size_t)N_ADJ * E_EDGES);     // 12.8 MB bf16
    u16*   s1      = s0 + (size_t)N_NODES * DIM;                 // 12.8 MB bf16 (= s0 + NVOFF)
    int2*  rowinfo = (int2*)(s1 + (size_t)N_NODES * DIM);        // 3.2 MB
    int*   gcnt    = (int*)(rowinfo + (size_t)N_ADJ * N_NODES);  // 6252 ints
    int*   bbase   = gcnt + NBTOT;                               // 6253 ints
    int*   cursor  = bbase + NBTOT + 1;                          // 6252 ints
    int*   used    = cursor + NBTOT;                             // 4 ints

    hipMemsetAsync(gcnt, 0, (size_t)NBTOT * sizeof(int), stream);

    mask_kernel<<<1, 64, 0, stream>>>(idxes_seq, idxes_res, used);
    gemm_kernel<<<N_NODES / 16, 256, 0, stream>>>(x, W, b, s0);

    dim3 egrid(P1_GRIDX, N_ADJ);
    hist_kernel <<<egrid, P1_BLK, 0, stream>>>(rows, gcnt, used);
    scan_kernel <<<1, P1_BLK, 0, stream>>>(gcnt, bbase, cursor);
    place_kernel<<<egrid, P1_BLK, 0, stream>>>(rows, cols, vals, cursor, bins, used);
    sort_kernel <<<NBTOT, 256, 0, stream>>>(bins, bbase, rowinfo, used);

    // s1 = 0.5*(A[i0]+A[i1]) @ s0
    gather_op_kernel<<<N_NODES / 4, 256, 0, stream>>>(s0, s1, bins, rowinfo, idxes_seq);
    // out = gelu(LN(0.5*(A[i2]+A[i3])@s1 + 0.5*(A[r0]+A[r1])@s0))
    fused_op_ln_gelu_kernel<<<N_NODES / 4, 256, 0, stream>>>(
        s0, out, bins, rowinfo, idxes_seq + 2, idxes_res, gamma, beta);
}

// Round 4
// 441.270 us; speedup vs baseline: 1.0023x; 1.0023x over previous
//
#include <hip/hip_runtime.h>
#include <hip/hip_bf16.h>
#include <math.h>

#define N_NODES 100000
#define DIM 64
#define E_EDGES 1600000
#define N_ADJ 4
#define NB 1563              // ceil(100000/64) buckets of 64 rows
#define NBTOT (N_ADJ * NB)   // 6252
#define P1_BLK 1024
#define P1_CHUNK 12800
#define P1_GRIDX 125         // 125 * 12800 = 1.6M
#define SORT_STAGE 4096      // per-bucket LDS stage; mean load 1024
#define NVOFF ((u32)N_NODES * DIM)   // u16 elements between s0 and s1

typedef unsigned short u16;
typedef unsigned int u32;

// ---- used-adjacency mask from device-side idxes ----
__global__ void mask_kernel(const int* __restrict__ iseq,
                            const int* __restrict__ ires,
                            int* __restrict__ used) {
    if (threadIdx.x == 0) {
        used[0] = used[1] = used[2] = used[3] = 0;
        used[iseq[0]] = 1; used[iseq[1]] = 1;
        used[iseq[2]] = 1; used[iseq[3]] = 1;
        used[ires[0]] = 1; used[ires[1]] = 1;
    }
}

// ---------------- GEMM: s0 = bf16(x @ W + b) ----------------
__global__ __launch_bounds__(256) void gemm_kernel(
    const float* __restrict__ x, const float* __restrict__ W,
    const float* __restrict__ b, u16* __restrict__ h) {
    __shared__ float Ws[DIM * DIM];
    __shared__ float xs[16 * DIM];
    const int tid = threadIdx.x;
    const long row0 = (long)blockIdx.x * 16;
    for (int i = tid; i < DIM * DIM; i += 256) Ws[i] = W[i];
    for (int i = tid; i < 16 * DIM; i += 256) xs[i] = x[row0 * DIM + i];
    __syncthreads();
    const int lane = tid & 63;
    const int grp  = tid >> 6;
    const float bias = b[lane];
    #pragma unroll
    for (int rr = 0; rr < 4; ++rr) {
        const int r = grp * 4 + rr;
        float acc = bias;
        #pragma unroll
        for (int k = 0; k < DIM; ++k)
            acc += xs[r * DIM + k] * Ws[k * DIM + lane];
        __hip_bfloat16 hb = __float2bfloat16(acc);
        h[(row0 + r) * DIM + lane] = *(u16*)&hb;
    }
}

// ---- hist: LDS-aggregated bucket counts -> gcnt ----
__global__ __launch_bounds__(1024) void hist_kernel(
    const int* __restrict__ rows, int* __restrict__ gcnt,
    const int* __restrict__ used) {
    __shared__ int h[NB];
    const int a = blockIdx.y;
    if (!used[a]) return;
    const int tid = threadIdx.x;
    const long e0 = (long)a * E_EDGES + (long)blockIdx.x * P1_CHUNK;
    for (int i = tid; i < NB; i += P1_BLK) h[i] = 0;
    __syncthreads();
    for (int i = tid; i < P1_CHUNK; i += P1_BLK)
        atomicAdd(&h[rows[e0 + i] >> 6], 1);
    __syncthreads();
    for (int bk = tid; bk < NB; bk += P1_BLK) {
        const int c = h[bk];
        if (c) atomicAdd(&gcnt[a * NB + bk], c);
    }
}

// ---- scan: exact exclusive scan of 6252 bucket counts (1 block) ----
__global__ __launch_bounds__(1024) void scan_kernel(
    const int* __restrict__ gcnt, int* __restrict__ bbase,
    int* __restrict__ cursor) {
    __shared__ int wsum[16];
    const int tid = threadIdx.x, lane = tid & 63, wave = tid >> 6;
    int pre[7];
    int tsum = 0;
    #pragma unroll
    for (int k = 0; k < 7; ++k) {
        const int idx = tid * 7 + k;
        const int v = (idx < NBTOT) ? gcnt[idx] : 0;
        pre[k] = tsum;
        tsum += v;
    }
    int incl = tsum;
    #pragma unroll
    for (int o = 1; o < 64; o <<= 1) {
        const int t = __shfl_up(incl, o);
        if (lane >= o) incl += t;
    }
    if (lane == 63) wsum[wave] = incl;
    __syncthreads();
    if (tid == 0) {
        int run = 0;
        #pragma unroll
        for (int w = 0; w < 16; ++w) { const int t = wsum[w]; wsum[w] = run; run += t; }
    }
    __syncthreads();
    const int texcl = incl - tsum + wsum[wave];
    #pragma unroll
    for (int k = 0; k < 7; ++k) {
        const int idx = tid * 7 + k;
        if (idx < NBTOT) {
            const int v = texcl + pre[k];
            bbase[idx]  = v;
            cursor[idx] = v;
        }
    }
    if (tid == 0) bbase[NBTOT] = N_ADJ * E_EDGES;
}

// ---- place: reserve per-(block,bucket) runs, pack edges ----
__global__ __launch_bounds__(1024) void place_kernel(
    const int* __restrict__ rows, const int* __restrict__ cols,
    const float* __restrict__ vals, int* __restrict__ cursor,
    int2* __restrict__ bins, const int* __restrict__ used) {
    __shared__ int h[NB];
    const int a = blockIdx.y;
    if (!used[a]) return;
    const int tid = threadIdx.x;
    const long e0 = (long)a * E_EDGES + (long)blockIdx.x * P1_CHUNK;
    for (int i = tid; i < NB; i += P1_BLK) h[i] = 0;
    __syncthreads();
    for (int i = tid; i < P1_CHUNK; i += P1_BLK)
        atomicAdd(&h[rows[e0 + i] >> 6], 1);
    __syncthreads();
    for (int bk = tid; bk < NB; bk += P1_BLK) {
        const int c = h[bk];
        if (c) h[bk] = atomicAdd(&cursor[a * NB + bk], c);  // abs base of run
    }
    __syncthreads();
    for (int i = tid; i < P1_CHUNK; i += P1_BLK) {
        const int r  = rows[e0 + i];
        const int bk = r >> 6;
        const int slot = atomicAdd(&h[bk], 1);              // absolute bins index
        bins[slot] = make_int2((cols[e0 + i] << 6) | (r & 63),
                               __float_as_int(vals[e0 + i]));
    }
}

// ---- sort: per-bucket counting sort by row&63, emit per-row (start,count) ----
__global__ __launch_bounds__(256) void sort_kernel(
    int2* __restrict__ bins, const int* __restrict__ bbase,
    int2* __restrict__ rowinfo, const int* __restrict__ used) {
    __shared__ int2 stage[SORT_STAGE];
    __shared__ int h[64], off[64], cur[64];
    const int a   = blockIdx.x / NB;
    if (!used[a]) return;
    const int tid = threadIdx.x;
    const int bk  = blockIdx.x % NB;
    const int p0  = bbase[blockIdx.x];
    const int n   = min(bbase[blockIdx.x + 1] - p0, SORT_STAGE);

    if (tid < 64) h[tid] = 0;
    __syncthreads();
    for (int i = tid; i < n; i += 256) {
        const int2 e = bins[p0 + i];
        stage[i] = e;
        atomicAdd(&h[e.x & 63], 1);
    }
    __syncthreads();
    if (tid < 64) {
        const int v = h[tid];
        int incl = v;
        #pragma unroll
        for (int o = 1; o < 64; o <<= 1) {
            const int t = __shfl_up(incl, o);
            if (tid >= o) incl += t;
        }
        off[tid] = incl - v;
        cur[tid] = incl - v;
    }
    __syncthreads();
    for (int i = tid; i < n; i += 256) {
        const int2 e = stage[i];
        const int rank = atomicAdd(&cur[e.x & 63], 1);
        bins[p0 + rank] = e;
    }
    if (tid < 64) {
        const int row = bk * 64 + tid;
        if (row < N_NODES)
            rowinfo[a * N_NODES + row] = make_int2(p0 + off[tid], h[tid]);
    }
}

// ---------------- Unified pull gather core (record-per-lane + LDS stage) ----
// Wave = 1 row. Per 64-edge super-iteration: each lane loads ONE edge record
// (cascade runs once per 64 edges), publishes (xm, v) to its per-wave LDS
// slot via one ds_write_b64. Then, phase-split with compile-time indices:
//   A: slot records read back (ds_read_b64, broadcast within 8-lane group)
//   B: slot gathers issued back-to-back (4 x global_load_dwordx4 per half)
//   C: unpack + FMA
// Slots 4..7 run under ONE wave-uniform branch (m is identical across the
// wave), so short rows (gather_op, m~32) skip 4 wasted 1KB gathers.
// Lanes with t >= m publish (0, 0.0f): harmless row-0 gather times zero.
__device__ __forceinline__ void gather4(
    const u16* __restrict__ base, const u32 nvoff,
    const int2* __restrict__ bins, uint2* __restrict__ stg,
    const int2 i0, const int2 i1, const int2 i2, const int2 i3,
    const int lane, const int grp, const int dsub, float acc[8])
{
    const int c1 = i0.y;
    const int c2 = c1 + i1.y;
    const int c3 = c2 + i2.y;
    const int m  = c3 + i3.y;
    const int b0 = i0.x;
    const int b1 = i1.x - c1;
    const int b2 = i2.x - c2;
    const int b3 = i3.x - c3;
    const u16* mybase = base + dsub;

    for (int t0 = 0; t0 < m; t0 += 64) {
        const int t = t0 + lane;
        u32  xm = 0u;
        float v = 0.f;
        if (t < m) {
            int pos = b0 + t;
            if (t >= c1) pos = b1 + t;
            if (t >= c2) pos = b2 + t;
            if (t >= c3) pos = b3 + t;
            const long long raw =
                __builtin_nontemporal_load((const long long*)(bins + pos));
            const int x = (int)raw;
            v  = __int_as_float((int)(raw >> 32));
            xm = ((u32)x & 0xFFFFFFC0u) + ((t < c2) ? nvoff : 0u);
        }
        stg[lane] = make_uint2(xm, (u32)__float_as_int(v));
        const int mrem = m - t0;
        const bool hi = (mrem > 32);     // wave-uniform (m same for all lanes)

        u32 xs0, xs1, xs2, xs3, xs4, xs5, xs6, xs7;
        float vs0, vs1, vs2, vs3, vs4, vs5, vs6, vs7;
        uint4 w0, w1, w2, w3, w4, w5, w6, w7;

        // ---- slots 0..3: records, then batched gathers ----
        {
            const uint2 r0 = stg[grp];
            const uint2 r1 = stg[8  + grp];
            const uint2 r2 = stg[16 + grp];
            const uint2 r3 = stg[24 + grp];
            xs0 = r0.x; vs0 = __int_as_float((int)r0.y);
            xs1 = r1.x; vs1 = __int_as_float((int)r1.y);
            xs2 = r2.x; vs2 = __int_as_float((int)r2.y);
            xs3 = r3.x; vs3 = __int_as_float((int)r3.y);
            w0 = *(const uint4*)(mybase + xs0);
            w1 = *(const uint4*)(mybase + xs1);
            w2 = *(const uint4*)(mybase + xs2);
            w3 = *(const uint4*)(mybase + xs3);
        }
        // ---- slots 4..7 under one uniform branch ----
        if (hi) {
            const uint2 r4 = stg[32 + grp];
            const uint2 r5 = stg[40 + grp];
            const uint2 r6 = stg[48 + grp];
            const uint2 r7 = stg[56 + grp];
            xs4 = r4.x; vs4 = __int_as_float((int)r4.y);
            xs5 = r5.x; vs5 = __int_as_float((int)r5.y);
            xs6 = r6.x; vs6 = __int_as_float((int)r6.y);
            xs7 = r7.x; vs7 = __int_as_float((int)r7.y);
            w4 = *(const uint4*)(mybase + xs4);
            w5 = *(const uint4*)(mybase + xs5);
            w6 = *(const uint4*)(mybase + xs6);
            w7 = *(const uint4*)(mybase + xs7);
        }

        #define FMA8(W, V) {                                                  \
            acc[0] = fmaf((V), __int_as_float((W).x << 16),         acc[0]);  \
            acc[1] = fmaf((V), __int_as_float((W).x & 0xffff0000u), acc[1]);  \
            acc[2] = fmaf((V), __int_as_float((W).y << 16),         acc[2]);  \
            acc[3] = fmaf((V), __int_as_float((W).y & 0xffff0000u), acc[3]);  \
            acc[4] = fmaf((V), __int_as_float((W).z << 16),         acc[4]);  \
            acc[5] = fmaf((V), __int_as_float((W).z & 0xffff0000u), acc[5]);  \
            acc[6] = fmaf((V), __int_as_float((W).w << 16),         acc[6]);  \
            acc[7] = fmaf((V), __int_as_float((W).w & 0xffff0000u), acc[7]); }
        FMA8(w0, vs0)
        FMA8(w1, vs1)
        FMA8(w2, vs2)
        FMA8(w3, vs3)
        if (hi) {
            FMA8(w4, vs4)
            FMA8(w5, vs5)
            FMA8(w6, vs6)
            FMA8(w7, vs7)
        }
        #undef FMA8
    }
}

__device__ __forceinline__ void reduce_groups8(float acc[8]) {
    #pragma unroll
    for (int d = 0; d < 8; ++d) {
        acc[d] += __shfl_xor(acc[d], 8);
        acc[d] += __shfl_xor(acc[d], 16);
        acc[d] += __shfl_xor(acc[d], 32);
    }
}

// s1 = bf16(0.5*(A[i0]+A[i1]) @ s0)
__global__ __launch_bounds__(256) void gather_op_kernel(
    const u16* __restrict__ s0, u16* __restrict__ dst,
    const int2* __restrict__ bins, const int2* __restrict__ rowinfo,
    const int* __restrict__ idx) {
    __shared__ uint2 stg[256];
    const int lane = threadIdx.x & 63;
    const int wave = threadIdx.x >> 6;
    const int row  = blockIdx.x * 4 + wave;
    const int grp  = lane >> 3;
    const int sub  = lane & 7;
    const int dsub = sub << 3;
    const int2 i0 = rowinfo[idx[0] * N_NODES + row];
    const int2 i1 = rowinfo[idx[1] * N_NODES + row];
    const int2 iz = make_int2(0, 0);
    float acc[8] = {0.f, 0.f, 0.f, 0.f, 0.f, 0.f, 0.f, 0.f};
    gather4(s0, 0u, bins, stg + wave * 64, i0, i1, iz, iz, lane, grp, dsub, acc);
    reduce_groups8(acc);
    if (grp == 0) {
        u32 p[4];
        #pragma unroll
        for (int q = 0; q < 4; ++q) {
            __hip_bfloat16 blo = __float2bfloat16(0.5f * acc[2 * q]);
            __hip_bfloat16 bhi = __float2bfloat16(0.5f * acc[2 * q + 1]);
            p[q] = (u32)(*(u16*)&blo) | ((u32)(*(u16*)&bhi) << 16);
        }
        *(uint4*)(dst + (long)row * DIM + dsub) = make_uint4(p[0], p[1], p[2], p[3]);
    }
}

// out = gelu(LN(0.5*(seq@s1) + 0.5*(res@s0)))
__global__ __launch_bounds__(256) void fused_op_ln_gelu_kernel(
    const u16* __restrict__ s0, float* __restrict__ out,
    const int2* __restrict__ bins, const int2* __restrict__ rowinfo,
    const int* __restrict__ idx_seq1, const int* __restrict__ idx_res,
    const float* __restrict__ gamma, const float* __restrict__ beta) {
    __shared__ uint2 stg[256];
    const int lane = threadIdx.x & 63;
    const int wave = threadIdx.x >> 6;
    const int row  = blockIdx.x * 4 + wave;
    const int grp  = lane >> 3;
    const int sub  = lane & 7;
    const int dsub = sub << 3;
    // segments 0,1 gather from s1 (= s0 + NVOFF, selected via nvoff), 2,3 from s0
    const int2 i0 = rowinfo[idx_seq1[0] * N_NODES + row];
    const int2 i1 = rowinfo[idx_seq1[1] * N_NODES + row];
    const int2 i2 = rowinfo[idx_res[0]  * N_NODES + row];
    const int2 i3 = rowinfo[idx_res[1]  * N_NODES + row];
    float acc[8] = {0.f, 0.f, 0.f, 0.f, 0.f, 0.f, 0.f, 0.f};
    gather4(s0, NVOFF, bins, stg + wave * 64, i0, i1, i2, i3, lane, grp, dsub, acc);
    reduce_groups8(acc);
    #pragma unroll
    for (int d = 0; d < 8; ++d) acc[d] *= 0.5f;
    float s = 0.f, s2 = 0.f;
    #pragma unroll
    for (int d = 0; d < 8; ++d) { s += acc[d]; s2 += acc[d] * acc[d]; }
    s  += __shfl_xor(s, 1);  s  += __shfl_xor(s, 2);  s  += __shfl_xor(s, 4);
    s2 += __shfl_xor(s2, 1); s2 += __shfl_xor(s2, 2); s2 += __shfl_xor(s2, 4);
    const float mu  = s * (1.0f / DIM);
    const float var = s2 * (1.0f / DIM) - mu * mu;
    const float inv = rsqrtf(var + 1e-5f);
    if (grp == 0) {
        const float4 gm0 = ((const float4*)gamma)[sub * 2];
        const float4 gm1 = ((const float4*)gamma)[sub * 2 + 1];
        const float4 bt0 = ((const float4*)beta)[sub * 2];
        const float4 bt1 = ((const float4*)beta)[sub * 2 + 1];
        float y[8];
        y[0] = (acc[0] - mu) * inv * gm0.x + bt0.x;
        y[1] = (acc[1] - mu) * inv * gm0.y + bt0.y;
        y[2] = (acc[2] - mu) * inv * gm0.z + bt0.z;
        y[3] = (acc[3] - mu) * inv * gm0.w + bt0.w;
        y[4] = (acc[4] - mu) * inv * gm1.x + bt1.x;
        y[5] = (acc[5] - mu) * inv * gm1.y + bt1.y;
        y[6] = (acc[6] - mu) * inv * gm1.z + bt1.z;
        y[7] = (acc[7] - mu) * inv * gm1.w + bt1.w;
        float4 o0, o1;
        o0.x = 0.5f * y[0] * (1.0f + erff(y[0] * 0.70710678118654752f));
        o0.y = 0.5f * y[1] * (1.0f + erff(y[1] * 0.70710678118654752f));
        o0.z = 0.5f * y[2] * (1.0f + erff(y[2] * 0.70710678118654752f));
        o0.w = 0.5f * y[3] * (1.0f + erff(y[3] * 0.70710678118654752f));
        o1.x = 0.5f * y[4] * (1.0f + erff(y[4] * 0.70710678118654752f));
        o1.y = 0.5f * y[5] * (1.0f + erff(y[5] * 0.70710678118654752f));
        o1.z = 0.5f * y[6] * (1.0f + erff(y[6] * 0.70710678118654752f));
        o1.w = 0.5f * y[7] * (1.0f + erff(y[7] * 0.70710678118654752f));
        float4* po = (float4*)(out + (long)row * DIM + dsub);
        po[0] = o0;
        po[1] = o1;
    }
}

extern "C" void kernel_launch(void* const* d_in, const int* in_sizes, int n_in,
                              void* d_out, int out_size, void* d_ws, size_t ws_size,
                              hipStream_t stream) {
    const float* x     = (const float*)d_in[0];
    const float* W     = (const float*)d_in[1];
    const float* b     = (const float*)d_in[2];
    const int*   rows  = (const int*)d_in[3];
    const int*   cols  = (const int*)d_in[4];
    const float* vals  = (const float*)d_in[5];
    const float* gamma = (const float*)d_in[6];
    const float* beta  = (const float*)d_in[7];
    const int*   idxes_seq = (const int*)d_in[8];   // [2,2] flat
    const int*   idxes_res = (const int*)d_in[9];   // [1,2] flat
    float* out = (float*)d_out;

    // workspace layout: ~80 MB total
    int2*  bins    = (int2*)d_ws;                                // 4E int2 = 51.2 MB
    u16*   s0      = (u16*)(bins + (size_t)N_ADJ * E_EDGES);     // 12.8 MB bf16
    u16*   s1      = s0 + (size_t)N_NODES * DIM;                 // 12.8 MB bf16 (= s0 + NVOFF)
    int2*  rowinfo = (int2*)(s1 + (size_t)N_NODES * DIM);        // 3.2 MB
    int*   gcnt    = (int*)(rowinfo + (size_t)N_ADJ * N_NODES);  // 6252 ints
    int*   bbase   = gcnt + NBTOT;                               // 6253 ints
    int*   cursor  = bbase + NBTOT + 1;                          // 6252 ints
    int*   used    = cursor + NBTOT;                             // 4 ints

    hipMemsetAsync(gcnt, 0, (size_t)NBTOT * sizeof(int), stream);

    mask_kernel<<<1, 64, 0, stream>>>(idxes_seq, idxes_res, used);
    gemm_kernel<<<N_NODES / 16, 256, 0, stream>>>(x, W, b, s0);

    dim3 egrid(P1_GRIDX, N_ADJ);
    hist_kernel <<<egrid, P1_BLK, 0, stream>>>(rows, gcnt, used);
    scan_kernel <<<1, P1_BLK, 0, stream>>>(gcnt, bbase, cursor);
    place_kernel<<<egrid, P1_BLK, 0, stream>>>(rows, cols, vals, cursor, bins, used);
    sort_kernel <<<NBTOT, 256, 0, stream>>>(bins, bbase, rowinfo, used);

    // s1 = 0.5*(A[i0]+A[i1]) @ s0
    gather_op_kernel<<<N_NODES / 4, 256, 0, stream>>>(s0, s1, bins, rowinfo, idxes_seq);
    // out = gelu(LN(0.5*(A[i2]+A[i3])@s1 + 0.5*(A[r0]+A[r1])@s0))
    fused_op_ln_gelu_kernel<<<N_NODES / 4, 256, 0, stream>>>(
        s0, out, bins, rowinfo, idxes_seq + 2, idxes_res, gamma, beta);
}